// Round 8
// baseline (1189.042 us; speedup 1.0000x reference)
//
#include <hip/hip_runtime.h>
#include <math.h>
#include <float.h>

#define B_   16
#define N_   4096
#define CIN  3
#define COUT 64
#define KNN  20
#define EPS_ 1e-5

// ---------------------------------------------------------------------------
// Workspace layout:
//   [0,   216): double stats[27]    (Sum e[6], Sum e e^T upper-tri[21])
//   [256, 768): float scale[64], shift[64]
//   [1024, 1024 + B*N*KNN*4): int idx[B*N*KNN]            (5242880 B)
//   [5243904, +B*N*4): int perm[B*N]   (Morton order)      (262144 B)
//   [5506048, +B*1024*4): int cellstart[B][1024]           (65536 B)
// ---------------------------------------------------------------------------

__device__ __forceinline__ unsigned expand10(unsigned v) {
    v = (v | (v << 16)) & 0x030000FFu;
    v = (v | (v << 8))  & 0x0300F00Fu;
    v = (v | (v << 4))  & 0x030C30C3u;
    v = (v | (v << 2))  & 0x09249249u;
    return v;
}
__device__ __forceinline__ unsigned quant10(float v) {
    int q = (int)((v + 4.0f) * 128.0f);
    return (unsigned)min(1023, max(0, q));
}

// ===========================================================================
// Kernel 0: per-batch Morton COUNTING sort (1024 buckets = top 10 morton
// bits = cells). Also emits cellstart[] (exclusive scan) for the pruned KNN.
// Any permutation is correctness-neutral; cell ranges are exact by
// construction (bucket = cell id).
// ===========================================================================
__global__ __launch_bounds__(1024) void morton_bucket_kernel(
    const float* __restrict__ x, int* __restrict__ perm,
    int* __restrict__ cellstart)
{
    __shared__ int hist[1024];
    __shared__ int scanbuf[1024];
    __shared__ int offs[1024];
    const int b = blockIdx.x, tid = threadIdx.x;
    const float* xb = x + (size_t)b * N_ * CIN;

    hist[tid] = 0;
    __syncthreads();

    int keys[4];
#pragma unroll
    for (int i = 0; i < 4; ++i) {
        int p = tid + i * 1024;
        float v0 = xb[p * 3 + 0], v1 = xb[p * 3 + 1], v2 = xb[p * 3 + 2];
        unsigned m = (expand10(quant10(v0)) << 2) |
                     (expand10(quant10(v1)) << 1) |
                      expand10(quant10(v2));
        keys[i] = (int)(m >> 20);          // cell id (10 bits)
        atomicAdd(&hist[keys[i]], 1);
    }
    __syncthreads();

    int v = hist[tid];
    scanbuf[tid] = v;
    __syncthreads();
    for (int off = 1; off < 1024; off <<= 1) {   // Hillis-Steele inclusive
        int t = (tid >= off) ? scanbuf[tid - off] : 0;
        __syncthreads();
        scanbuf[tid] += t;
        __syncthreads();
    }
    int excl = scanbuf[tid] - v;
    offs[tid] = excl;
    cellstart[b * 1024 + tid] = excl;            // exact cell ranges
    __syncthreads();

#pragma unroll
    for (int i = 0; i < 4; ++i) {
        int p = tid + i * 1024;
        int pos = atomicAdd(&offs[keys[i]], 1);
        perm[b * N_ + pos] = p;
    }
}

// ===========================================================================
// Kernel 1: exact-match KNN (top-20, jax top_k semantics) + BN stats,
// with EXACT octree-cell pruning.
//
// r7 lesson: every wave owes an exact per-quarter top-20, so with contiguous
// morton quarters 3/4 waves do full random-law insert work (105
// instr/candidate measured). Fix: quarter = cell-interleave ((c&3)==q, a
// z/x checkerboard) so every wave has near candidates and a tight bound,
// plus AABB pruning so hopeless cells are never examined.
//
// Exactness argument:
//  * selection state = 20 smallest u64 keys (sortable_fp32(d)<<32 | orig_j):
//    result independent of visit order / subset split; merge = union.
//  * distance d bit-identical to np ref (fp32 expansion form, verified r3+).
//  * a cell may be skipped only if min-dist(cell AABB, row)^2 > worst_d
//    with margin *1.0002+1e-3, which dwarfs the <=1.3e-5 fp32 error of the
//    expansion form and the ~1e-6 AABB/quantization rounding.
//  * clamped outliers (|v|>4): edge cells expand to +-1e30 in that direction.
//  * sentinels ~0ull-k are distinct, larger than any real key, and keep
//    bound=+huge until all 20 slots hold real keys (no pruning during fill).
// ===========================================================================
__global__ __launch_bounds__(512) void knn_prune_kernel(
    const float* __restrict__ x, const int* __restrict__ perm,
    const int* __restrict__ cellstart,
    int* __restrict__ idx_out, double* __restrict__ stats)
{
    __shared__ __align__(16) char smem[65536];
    float4* pts = (float4*)smem;                         // {x,y,z,bitcast(j)}
    unsigned long long* scr = (unsigned long long*)smem; // merge-scratch view

    const int b    = blockIdx.y;
    const int tid  = threadIdx.x;
    const int wave = tid >> 6;
    const int lane = tid & 63;
    const int r    = wave >> 2;     // row-group 0..1
    const int q    = wave & 3;      // cell-interleave class
    const float* xb = x + (size_t)b * N_ * CIN;
    const int cbase = b * 1024;

    // stage in MORTON order: pts[pos] = {x,y,z, bits(orig_j)}
    for (int p = tid; p < N_; p += 512) {
        int j = perm[b * N_ + p];                        // coalesced
        pts[p] = make_float4(xb[j * 3 + 0], xb[j * 3 + 1], xb[j * 3 + 2],
                             __int_as_float(j));
    }
    __syncthreads();

    const int rowg = blockIdx.x * 128 + r * 64;          // wave's first row pos
    const float4 xf = pts[rowg + lane];
    const int jrow  = __float_as_int(xf.w);
    const float sqi = __fadd_rn(__fadd_rn(__fmul_rn(xf.x, xf.x),
                                          __fmul_rn(xf.y, xf.y)),
                                __fmul_rn(xf.z, xf.z));

    // rotation anchor: supercell (7-bit prefix) of the wave's rows
    unsigned mrow = (expand10(quant10(xf.x)) << 2) |
                    (expand10(quant10(xf.y)) << 1) |
                     expand10(quant10(xf.z));
    const int sc_start = __builtin_amdgcn_readfirstlane((int)(mrow >> 23));

    auto mkkey = [&](float4 p) -> unsigned long long {
        float sqj = __fadd_rn(__fadd_rn(__fmul_rn(p.x, p.x),
                                        __fmul_rn(p.y, p.y)),
                              __fmul_rn(p.z, p.z));
        float dot = __fadd_rn(__fadd_rn(__fmul_rn(xf.x, p.x),
                                        __fmul_rn(xf.y, p.y)),
                              __fmul_rn(xf.z, p.z));
        float d = __fsub_rn(__fadd_rn(sqi, sqj), __fmul_rn(2.0f, dot));
        unsigned u = __float_as_uint(d);
        unsigned s = u ^ (0x80000000u | (unsigned)((int)u >> 31));
        return ((unsigned long long)s << 32) |
               (unsigned)__float_as_int(p.w);
    };

    unsigned long long bk[KNN];
#pragma unroll
    for (int k = 0; k < KNN; ++k) bk[k] = ~0ull - (unsigned long long)k;
    unsigned long long worst = ~0ull;
    float bound = 1e30f;            // prune threshold (worst_d with margin)

    // replace-by-value insert (keys unique incl. sentinels); updates bound
    auto insert = [&](unsigned long long key) {
        if (key < worst) {
            unsigned long long oldw = worst, nw = 0;
#pragma unroll
            for (int k = 0; k < KNN; ++k) {
                bk[k] = (bk[k] == oldw) ? key : bk[k];
                nw = bk[k] > nw ? bk[k] : nw;
            }
            worst = nw;
            unsigned s = (unsigned)(nw >> 32);
            unsigned u = (s >= 0x80000000u) ? (s ^ 0x80000000u) : ~s;
            float wd = (s == 0xFFFFFFFFu) ? 1e30f : __uint_as_float(u);
            bound = wd * 1.0002f + 1e-3f;
        }
    };

    // cell-id bit layout (from morton top-10): [x9 y9 z9 x8 y8 z8 x7 y7 z7 x6]
    for (int t = 0; t < 128; ++t) {
        int sc = (sc_start + t) & 127;                   // rotated: own sc first
        // supercell AABB: px={x9x8x7} w=1.0, py={y9y8} w=2.0, pz={z9z8} w=2.0
        int pxs = ((sc >> 4) & 4) | ((sc >> 2) & 2) | (sc & 1);
        int pys = ((sc >> 4) & 2) | ((sc >> 2) & 1);
        int pzs = ((sc >> 3) & 2) | ((sc >> 1) & 1);
        float xlo = pxs ? pxs * 1.0f - 4.0f : -1e30f;
        float xhi = (pxs == 7) ? 1e30f : pxs * 1.0f - 3.0f;
        float ylo = pys ? pys * 2.0f - 4.0f : -1e30f;
        float yhi = (pys == 3) ? 1e30f : pys * 2.0f - 2.0f;
        float zlo = pzs ? pzs * 2.0f - 4.0f : -1e30f;
        float zhi = (pzs == 3) ? 1e30f : pzs * 2.0f - 2.0f;
        float dx = fmaxf(fmaxf(xlo - xf.x, xf.x - xhi), 0.0f);
        float dy = fmaxf(fmaxf(ylo - xf.y, xf.y - yhi), 0.0f);
        float dz = fmaxf(fmaxf(zlo - xf.z, xf.z - zhi), 0.0f);
        float m2 = dx * dx + dy * dy + dz * dz;
        if (!__any(m2 <= bound)) continue;

#pragma unroll
        for (int h = 0; h < 2; ++h) {
            int c  = sc * 8 + q + h * 4;                 // (c&3)==q checkerboard
            int cs = cellstart[cbase + c];
            int ce = (c < 1023) ? cellstart[cbase + c + 1] : N_;
            if (cs >= ce) continue;
            // cell AABB: px={x9x8x7x6} w=0.5, py={y9y8y7} w=1.0, pz w=1.0
            int px = ((c >> 6) & 8) | ((c >> 4) & 4) | ((c >> 2) & 2) | (c & 1);
            int py = ((c >> 6) & 4) | ((c >> 4) & 2) | ((c >> 2) & 1);
            int pz = ((c >> 5) & 4) | ((c >> 3) & 2) | ((c >> 1) & 1);
            float cx0 = px ? px * 0.5f - 4.0f : -1e30f;
            float cx1 = (px == 15) ? 1e30f : px * 0.5f - 3.5f;
            float cy0 = py ? py * 1.0f - 4.0f : -1e30f;
            float cy1 = (py == 7) ? 1e30f : py * 1.0f - 3.0f;
            float cz0 = pz ? pz * 1.0f - 4.0f : -1e30f;
            float cz1 = (pz == 7) ? 1e30f : pz * 1.0f - 3.0f;
            float ex = fmaxf(fmaxf(cx0 - xf.x, xf.x - cx1), 0.0f);
            float ey = fmaxf(fmaxf(cy0 - xf.y, xf.y - cy1), 0.0f);
            float ez = fmaxf(fmaxf(cz0 - xf.z, xf.z - cz1), 0.0f);
            float cm2 = ex * ex + ey * ey + ez * ez;
            if (!__any(cm2 <= bound)) continue;

            for (int p = cs; p < ce; ++p) {              // ~4 pts/cell avg
                unsigned long long key = mkkey(pts[p]);  // uniform addr -> bcast
                insert(key);
            }
        }
    }
    __syncthreads();    // scans done; pts dead (xf in regs) -> scr valid

    // merge round A: q1 -> slot0, q3 -> slot1   (40KB <= 64KB)
    if (q & 1) {
        int base = ((r * 2 + (q >> 1)) * 64 + lane) * KNN;
#pragma unroll
        for (int k = 0; k < KNN; ++k) scr[base + k] = bk[k];
    }
    __syncthreads();
    if (!(q & 1)) {                 // q0 absorbs q1; q2 absorbs q3
        int base = ((r * 2 + (q >> 1)) * 64 + lane) * KNN;
#pragma unroll
        for (int k = 0; k < KNN; ++k) insert(scr[base + k]);
    }
    __syncthreads();
    // merge round B: q2 -> slot1; q0 absorbs
    if (q == 2) {
        int base = ((r * 2 + 1) * 64 + lane) * KNN;
#pragma unroll
        for (int k = 0; k < KNN; ++k) scr[base + k] = bk[k];
    }
    __syncthreads();
    if (q == 0) {
        int base = ((r * 2 + 1) * 64 + lane) * KNN;
#pragma unroll
        for (int k = 0; k < KNN; ++k) insert(scr[base + k]);

        const long long row = (long long)b * N_ + jrow;
        int bi[KNN];
#pragma unroll
        for (int k = 0; k < KNN; ++k) bi[k] = (int)(bk[k] & 0xFFFFFFFFull);
#pragma unroll
        for (int k = 0; k < KNN; ++k) idx_out[row * KNN + k] = bi[k];

        // --- BN statistics (neighbor coords from global; batch slab is hot)
        float acc[27];
#pragma unroll
        for (int t = 0; t < 27; ++t) acc[t] = 0.0f;
#pragma unroll
        for (int k = 0; k < KNN; ++k) {
            const float* pj = xb + bi[k] * 3;
            float e[6] = { xf.x, xf.y, xf.z,
                           pj[0] - xf.x, pj[1] - xf.y, pj[2] - xf.z };
            int t = 6;
#pragma unroll
            for (int a = 0; a < 6; ++a) {
                acc[a] += e[a];
#pragma unroll
                for (int bb = a; bb < 6; ++bb) acc[t++] += e[a] * e[bb];
            }
        }
#pragma unroll
        for (int t = 0; t < 27; ++t) {
            float v = acc[t];
            v += __shfl_down(v, 32); v += __shfl_down(v, 16);
            v += __shfl_down(v, 8);  v += __shfl_down(v, 4);
            v += __shfl_down(v, 2);  v += __shfl_down(v, 1);
            acc[t] = v;
        }
        if (lane == 0) {
#pragma unroll
            for (int t = 0; t < 27; ++t) atomicAdd(&stats[t], (double)acc[t]);
        }
    }
}

// ===========================================================================
// Kernel 2: fold stats -> per-channel scale/shift (fp64, 64 threads)
// ===========================================================================
__global__ void bn_prep_kernel(
    const double* __restrict__ stats,
    const float* __restrict__ w1, const float* __restrict__ b1,
    const float* __restrict__ gamma, const float* __restrict__ beta,
    float* __restrict__ scale_shift)
{
    const int c = threadIdx.x;
    double s[6], S[6][6];
#pragma unroll
    for (int a = 0; a < 6; ++a) s[a] = stats[a];
    int t = 6;
#pragma unroll
    for (int a = 0; a < 6; ++a)
#pragma unroll
        for (int bb = a; bb < 6; ++bb) { S[a][bb] = stats[t]; S[bb][a] = stats[t]; ++t; }

    const double M = (double)B_ * N_ * KNN;
    double wc[6];
#pragma unroll
    for (int j = 0; j < 6; ++j) wc[j] = (double)w1[j * COUT + c];
    const double b1c = (double)b1[c];

    double sw = 0.0;
#pragma unroll
    for (int j = 0; j < 6; ++j) sw += s[j] * wc[j];
    double mean = sw / M + b1c;

    double qq = 0.0;
#pragma unroll
    for (int a = 0; a < 6; ++a)
#pragma unroll
        for (int bb = 0; bb < 6; ++bb) qq += S[a][bb] * wc[a] * wc[bb];
    double ex2 = (qq + 2.0 * b1c * sw) / M + b1c * b1c;
    double var = ex2 - mean * mean;

    double sc = (double)gamma[c] / sqrt(var + (double)EPS_);
    double sh = (double)beta[c] - mean * sc;
    scale_shift[c]        = (float)sc;
    scale_shift[COUT + c] = (float)sh;
}

// ===========================================================================
// Kernel 3: fused edge-feature -> lin1 -> BN -> ReLU -> lin2 -> max over K.
// 8 rows per wave; rows processed in pairs packed [k][d][pair] in LDS.
// ===========================================================================
__global__ __launch_bounds__(256) void mlp_max_kernel(
    const float* __restrict__ x, const int* __restrict__ idx,
    const float* __restrict__ w1, const float* __restrict__ b1,
    const float* __restrict__ scale_shift,
    const float* __restrict__ w2, const float* __restrict__ b2,
    float* __restrict__ out)
{
    __shared__ __align__(16) float h2[4][KNN][COUT][2];   // 40 KB

    const int tid = threadIdx.x;
    const int wv  = tid >> 6;
    const int c   = tid & 63;

    float w1c[6];
#pragma unroll
    for (int j = 0; j < 6; ++j) w1c[j] = w1[j * COUT + c];
    const float b1c = b1[c];
    const float sc  = scale_shift[c];
    const float sh  = scale_shift[COUT + c];
    const float b2c = b2[c];
    float w2c[COUT];
#pragma unroll
    for (int d = 0; d < COUT; ++d) w2c[d] = w2[d * COUT + c];

    const int rowbase = (blockIdx.x * 4 + wv) * 8;

    for (int pair = 0; pair < 4; ++pair) {
        const int ra = rowbase + pair * 2;
#pragma unroll
        for (int rr = 0; rr < 2; ++rr) {
            const int row = ra + rr;
            const int b   = row >> 12;
            const float xi0 = x[row * 3 + 0];
            const float xi1 = x[row * 3 + 1];
            const float xi2 = x[row * 3 + 2];
#pragma unroll
            for (int k = 0; k < KNN; ++k) {
                int j = idx[row * KNN + k];               // wave-uniform
                const float* pj = x + ((size_t)b * N_ + j) * 3;
                float e3 = pj[0] - xi0, e4 = pj[1] - xi1, e5 = pj[2] - xi2;
                float h = b1c;
                h = fmaf(xi0, w1c[0], h); h = fmaf(xi1, w1c[1], h);
                h = fmaf(xi2, w1c[2], h); h = fmaf(e3,  w1c[3], h);
                h = fmaf(e4,  w1c[4], h); h = fmaf(e5,  w1c[5], h);
                h = fmaf(h, sc, sh);
                h2[wv][k][c][rr] = fmaxf(h, 0.0f);        // 2-way bank alias: free
            }
        }
        __syncthreads();   // uniform across the block's 4 waves

        float mxa = -INFINITY, mxb = -INFINITY;
        for (int k = 0; k < KNN; ++k) {
            float aa = b2c, ab = b2c;
#pragma unroll
            for (int d2 = 0; d2 < COUT / 2; ++d2) {
                float4 hv = *(const float4*)&h2[wv][k][d2 * 2][0]; // broadcast
                aa = fmaf(hv.x, w2c[d2 * 2 + 0], aa);
                ab = fmaf(hv.y, w2c[d2 * 2 + 0], ab);
                aa = fmaf(hv.z, w2c[d2 * 2 + 1], aa);
                ab = fmaf(hv.w, w2c[d2 * 2 + 1], ab);
            }
            mxa = fmaxf(mxa, aa); mxb = fmaxf(mxb, ab);
        }
        out[(size_t)ra * COUT + c]       = mxa;
        out[(size_t)(ra + 1) * COUT + c] = mxb;
        __syncthreads();   // protect h2 reuse next pair
    }
}

// ===========================================================================
extern "C" void kernel_launch(void* const* d_in, const int* in_sizes, int n_in,
                              void* d_out, int out_size, void* d_ws, size_t ws_size,
                              hipStream_t stream)
{
    const float* x     = (const float*)d_in[0];
    const float* w1    = (const float*)d_in[2];
    const float* b1    = (const float*)d_in[3];
    const float* gamma = (const float*)d_in[4];
    const float* beta  = (const float*)d_in[5];
    const float* w2    = (const float*)d_in[6];
    const float* b2    = (const float*)d_in[7];
    float* out = (float*)d_out;

    char*   ws          = (char*)d_ws;
    double* stats       = (double*)ws;
    float*  scale_shift = (float*)(ws + 256);
    int*    idx         = (int*)(ws + 1024);
    int*    perm        = (int*)(ws + 1024 + (size_t)B_ * N_ * KNN * 4);
    int*    cellstart   = (int*)(ws + 1024 + (size_t)B_ * N_ * KNN * 4
                                      + (size_t)B_ * N_ * 4);

    hipMemsetAsync(stats, 0, 27 * sizeof(double), stream);
    morton_bucket_kernel<<<B_, 1024, 0, stream>>>(x, perm, cellstart);
    knn_prune_kernel<<<dim3(32, 16), 512, 0, stream>>>(x, perm, cellstart,
                                                       idx, stats);
    bn_prep_kernel<<<1, COUT, 0, stream>>>(stats, w1, b1, gamma, beta, scale_shift);
    mlp_max_kernel<<<(B_ * N_) / 32, 256, 0, stream>>>(x, idx, w1, b1, scale_shift,
                                                       w2, b2, out);
}

// Round 9
// 865.076 us; speedup vs baseline: 1.3745x; 1.3745x over previous
//
#include <hip/hip_runtime.h>
#include <math.h>
#include <float.h>

#define B_   16
#define N_   4096
#define CIN  3
#define COUT 64
#define KNN  20
#define EPS_ 1e-5

// ---------------------------------------------------------------------------
// Workspace layout:
//   [0,   216): double stats[27]    (Sum e[6], Sum e e^T upper-tri[21])
//   [256, 768): float scale[64], shift[64]
//   [1024, 1024 + B*N*KNN*4): int idx[B*N*KNN]           (5242880 B)
//   [5243904, +B*N*4): int perm[B*N]  (Morton row order)  (262144 B)
// ---------------------------------------------------------------------------

__device__ __forceinline__ unsigned expand10(unsigned v) {
    v = (v | (v << 16)) & 0x030000FFu;
    v = (v | (v << 8))  & 0x0300F00Fu;
    v = (v | (v << 4))  & 0x030C30C3u;
    v = (v | (v << 2))  & 0x09249249u;
    return v;
}
__device__ __forceinline__ unsigned quant10(float v) {
    int q = (int)((v + 4.0f) * 128.0f);
    return (unsigned)min(1023, max(0, q));
}

// ===========================================================================
// Kernel 0: per-batch Morton COUNTING sort (1024 buckets = top 10 morton
// bits). PERFORMANCE ONLY: any permutation is correctness-neutral.
// ===========================================================================
__global__ __launch_bounds__(1024) void morton_bucket_kernel(
    const float* __restrict__ x, int* __restrict__ perm)
{
    __shared__ int hist[1024];
    __shared__ int scanbuf[1024];
    __shared__ int offs[1024];
    const int b = blockIdx.x, tid = threadIdx.x;
    const float* xb = x + (size_t)b * N_ * CIN;

    hist[tid] = 0;
    __syncthreads();

    int keys[4];
#pragma unroll
    for (int i = 0; i < 4; ++i) {
        int p = tid + i * 1024;
        float v0 = xb[p * 3 + 0], v1 = xb[p * 3 + 1], v2 = xb[p * 3 + 2];
        unsigned m = (expand10(quant10(v0)) << 2) |
                     (expand10(quant10(v1)) << 1) |
                      expand10(quant10(v2));
        keys[i] = (int)(m >> 20);          // top 10 bits
        atomicAdd(&hist[keys[i]], 1);
    }
    __syncthreads();

    int v = hist[tid];
    scanbuf[tid] = v;
    __syncthreads();
    for (int off = 1; off < 1024; off <<= 1) {   // Hillis-Steele inclusive
        int t = (tid >= off) ? scanbuf[tid - off] : 0;
        __syncthreads();
        scanbuf[tid] += t;
        __syncthreads();
    }
    offs[tid] = scanbuf[tid] - v;                // exclusive base
    __syncthreads();

#pragma unroll
    for (int i = 0; i < 4; ++i) {
        int p = tid + i * 1024;
        int pos = atomicAdd(&offs[keys[i]], 1);
        perm[b * N_ + pos] = p;
    }
}

// ===========================================================================
// Kernel 1: exact-match KNN (top-20, jax top_k semantics) + BN stats.
// Distance: fp32 EXPANSION form, bit-identical to np ref (verified r3-r8).
// Selection: 20 smallest u64 keys (sortable_fp32(d)<<32 | orig_j) — exact
// top_k with lowest-index tie-break, INDEPENDENT of candidate visit order
// and of how candidates are partitioned across waves (merge = union).
//
// Round-9 structure: r7 throughput skeleton (group-of-4 unrolled broadcast
// reads, branch-light reject path) + MOD-4 INTERLEAVED quarters.
//   r7 lesson: contiguous morton quarters -> ball prefill tight for only the
//     1 wave whose quarter contains its rows; the other 3 clamp to the
//     quarter edge -> loose worst -> random-law insert storm (105
//     instr/candidate measured ~ avg of 1 tight + 3 loose waves).
//   r8 lesson: cell pruning removed work but destroyed the throughput shape
//     (serial dependent LDS loop, VALUBusy 67->36, 824us). Reverted.
//   r9: quarter q = morton positions p with (p&3)==q. Every quarter is a
//     spatially-uniform 1/4 subsample -> EVERY wave's prefill (20 positions
//     stepping by 4 around its rows) is a tight spatial ball -> tight
//     initial worst for all 8 waves; shuffled scan keeps insert prob
//     decaying. Skeleton instructions unchanged from r7 otherwise.
// ===========================================================================
__global__ __launch_bounds__(512) void knn_inter_kernel(
    const float* __restrict__ x, const int* __restrict__ perm,
    int* __restrict__ idx_out, double* __restrict__ stats)
{
    __shared__ __align__(16) char smem[65536];
    float4* pts = (float4*)smem;                         // {x,y,z,bitcast(j)}
    unsigned long long* scr = (unsigned long long*)smem; // merge-scratch view

    const int b    = blockIdx.y;
    const int tid  = threadIdx.x;
    const int wave = tid >> 6;
    const int lane = tid & 63;
    const int r    = wave >> 2;     // row-group 0..1
    const int q    = wave & 3;      // interleave class: positions p&3==q
    const float* xb = x + (size_t)b * N_ * CIN;

    // stage in MORTON order: pts[pos] = {x,y,z, bits(orig_j)}
    for (int p = tid; p < N_; p += 512) {
        int j = perm[b * N_ + p];                        // coalesced
        pts[p] = make_float4(xb[j * 3 + 0], xb[j * 3 + 1], xb[j * 3 + 2],
                             __int_as_float(j));
    }
    __syncthreads();

    // rows: morton positions; orig row index from .w
    const int rowg = blockIdx.x * 128 + r * 64;          // wave's first row pos
    const float4 xf = pts[rowg + lane];
    const int jrow  = __float_as_int(xf.w);
    const float sqi = __fadd_rn(__fadd_rn(__fmul_rn(xf.x, xf.x),
                                          __fmul_rn(xf.y, xf.y)),
                                __fmul_rn(xf.z, xf.z));

    auto mkkey = [&](float4 p) -> unsigned long long {
        float sqj = __fadd_rn(__fadd_rn(__fmul_rn(p.x, p.x),
                                        __fmul_rn(p.y, p.y)),
                              __fmul_rn(p.z, p.z));
        float dot = __fadd_rn(__fadd_rn(__fmul_rn(xf.x, p.x),
                                        __fmul_rn(xf.y, p.y)),
                              __fmul_rn(xf.z, p.z));
        float d = __fsub_rn(__fadd_rn(sqi, sqj), __fmul_rn(2.0f, dot));
        unsigned u = __float_as_uint(d);
        unsigned s = u ^ (0x80000000u | (unsigned)((int)u >> 31));
        return ((unsigned long long)s << 32) |
               (unsigned)__float_as_int(p.w);
    };

    // quarter-index anchor: t in [0,1024), candidate position = 4t+q.
    // ta = rowg>>2 puts prefill positions within +-80 morton slots of the
    // rows for EVERY q — tight ball for all waves (wave-uniform SGPR math).
    const int ta = rowg >> 2;

    unsigned long long bk[KNN];
    unsigned long long worst;

    // prefill: 20 ball candidates (t = ta..ta+19 wrap, p = 4t+q)
#pragma unroll
    for (int k = 0; k < KNN; ++k)
        bk[k] = mkkey(pts[4 * ((ta + k) & 1023) + q]);
    {
        unsigned long long w = 0;
#pragma unroll
        for (int k = 0; k < KNN; ++k) w = bk[k] > w ? bk[k] : w;
        worst = w;
    }

    // replace-by-value insert: keys unique -> exactly one slot matches worst
    auto insert = [&](unsigned long long key) {
        if (key < worst) {
            unsigned long long oldw = worst, nw = 0;
#pragma unroll
            for (int k = 0; k < KNN; ++k) {
                bk[k] = (bk[k] == oldw) ? key : bk[k];
                nw = bk[k] > nw ? bk[k] : nw;
            }
            worst = nw;
        }
    };

    // shuffled scan: v = (s*509) & 1023 is a bijection on [0,1024);
    // v<20 are the prefill t-offsets -> masked with sentinel (never inserts).
    for (int s = 0; s < 1024; s += 4) {
        int v0 = ((s + 0) * 509) & 1023;     // wave-uniform (SGPR math)
        int v1 = ((s + 1) * 509) & 1023;
        int v2 = ((s + 2) * 509) & 1023;
        int v3 = ((s + 3) * 509) & 1023;
        float4 a0 = pts[4 * ((ta + v0) & 1023) + q];
        float4 a1 = pts[4 * ((ta + v1) & 1023) + q];
        float4 a2 = pts[4 * ((ta + v2) & 1023) + q];
        float4 a3 = pts[4 * ((ta + v3) & 1023) + q];
        unsigned long long k0 = (v0 < 20) ? ~0ull : mkkey(a0);
        unsigned long long k1 = (v1 < 20) ? ~0ull : mkkey(a1);
        unsigned long long k2 = (v2 < 20) ? ~0ull : mkkey(a2);
        unsigned long long k3 = (v3 < 20) ? ~0ull : mkkey(a3);
        if ((k0 < worst) | (k1 < worst) | (k2 < worst) | (k3 < worst)) {
            insert(k0); insert(k1); insert(k2); insert(k3);
        }
    }
    __syncthreads();    // scans done; pts dead (xf in regs) -> scr valid

    // merge round A: q1 -> slot0, q3 -> slot1   (40KB <= 64KB)
    if (q & 1) {
        int base = ((r * 2 + (q >> 1)) * 64 + lane) * KNN;
#pragma unroll
        for (int k = 0; k < KNN; ++k) scr[base + k] = bk[k];
    }
    __syncthreads();
    if (!(q & 1)) {                 // q0 absorbs q1; q2 absorbs q3
        int base = ((r * 2 + (q >> 1)) * 64 + lane) * KNN;
#pragma unroll
        for (int k = 0; k < KNN; ++k) insert(scr[base + k]);
    }
    __syncthreads();
    // merge round B: q2 -> slot1; q0 absorbs
    if (q == 2) {
        int base = ((r * 2 + 1) * 64 + lane) * KNN;
#pragma unroll
        for (int k = 0; k < KNN; ++k) scr[base + k] = bk[k];
    }
    __syncthreads();
    if (q == 0) {
        int base = ((r * 2 + 1) * 64 + lane) * KNN;
#pragma unroll
        for (int k = 0; k < KNN; ++k) insert(scr[base + k]);

        const long long row = (long long)b * N_ + jrow;
        int bi[KNN];
#pragma unroll
        for (int k = 0; k < KNN; ++k) bi[k] = (int)(bk[k] & 0xFFFFFFFFull);
#pragma unroll
        for (int k = 0; k < KNN; ++k) idx_out[row * KNN + k] = bi[k];

        // --- BN statistics (neighbor coords from global; batch slab is hot)
        float acc[27];
#pragma unroll
        for (int t = 0; t < 27; ++t) acc[t] = 0.0f;
#pragma unroll
        for (int k = 0; k < KNN; ++k) {
            const float* pj = xb + bi[k] * 3;
            float e[6] = { xf.x, xf.y, xf.z,
                           pj[0] - xf.x, pj[1] - xf.y, pj[2] - xf.z };
            int t = 6;
#pragma unroll
            for (int a = 0; a < 6; ++a) {
                acc[a] += e[a];
#pragma unroll
                for (int bb = a; bb < 6; ++bb) acc[t++] += e[a] * e[bb];
            }
        }
#pragma unroll
        for (int t = 0; t < 27; ++t) {
            float v = acc[t];
            v += __shfl_down(v, 32); v += __shfl_down(v, 16);
            v += __shfl_down(v, 8);  v += __shfl_down(v, 4);
            v += __shfl_down(v, 2);  v += __shfl_down(v, 1);
            acc[t] = v;
        }
        if (lane == 0) {
#pragma unroll
            for (int t = 0; t < 27; ++t) atomicAdd(&stats[t], (double)acc[t]);
        }
    }
}

// ===========================================================================
// Kernel 2: fold stats -> per-channel scale/shift (fp64, 64 threads)
// ===========================================================================
__global__ void bn_prep_kernel(
    const double* __restrict__ stats,
    const float* __restrict__ w1, const float* __restrict__ b1,
    const float* __restrict__ gamma, const float* __restrict__ beta,
    float* __restrict__ scale_shift)
{
    const int c = threadIdx.x;
    double s[6], S[6][6];
#pragma unroll
    for (int a = 0; a < 6; ++a) s[a] = stats[a];
    int t = 6;
#pragma unroll
    for (int a = 0; a < 6; ++a)
#pragma unroll
        for (int bb = a; bb < 6; ++bb) { S[a][bb] = stats[t]; S[bb][a] = stats[t]; ++t; }

    const double M = (double)B_ * N_ * KNN;
    double wc[6];
#pragma unroll
    for (int j = 0; j < 6; ++j) wc[j] = (double)w1[j * COUT + c];
    const double b1c = (double)b1[c];

    double sw = 0.0;
#pragma unroll
    for (int j = 0; j < 6; ++j) sw += s[j] * wc[j];
    double mean = sw / M + b1c;

    double qq = 0.0;
#pragma unroll
    for (int a = 0; a < 6; ++a)
#pragma unroll
        for (int bb = 0; bb < 6; ++bb) qq += S[a][bb] * wc[a] * wc[bb];
    double ex2 = (qq + 2.0 * b1c * sw) / M + b1c * b1c;
    double var = ex2 - mean * mean;

    double sc = (double)gamma[c] / sqrt(var + (double)EPS_);
    double sh = (double)beta[c] - mean * sc;
    scale_shift[c]        = (float)sc;
    scale_shift[COUT + c] = (float)sh;
}

// ===========================================================================
// Kernel 3: fused edge-feature -> lin1 -> BN -> ReLU -> lin2 -> max over K.
// 8 rows per wave; rows processed in pairs packed [k][d][pair] in LDS.
// ===========================================================================
__global__ __launch_bounds__(256) void mlp_max_kernel(
    const float* __restrict__ x, const int* __restrict__ idx,
    const float* __restrict__ w1, const float* __restrict__ b1,
    const float* __restrict__ scale_shift,
    const float* __restrict__ w2, const float* __restrict__ b2,
    float* __restrict__ out)
{
    __shared__ __align__(16) float h2[4][KNN][COUT][2];   // 40 KB

    const int tid = threadIdx.x;
    const int wv  = tid >> 6;
    const int c   = tid & 63;

    float w1c[6];
#pragma unroll
    for (int j = 0; j < 6; ++j) w1c[j] = w1[j * COUT + c];
    const float b1c = b1[c];
    const float sc  = scale_shift[c];
    const float sh  = scale_shift[COUT + c];
    const float b2c = b2[c];
    float w2c[COUT];
#pragma unroll
    for (int d = 0; d < COUT; ++d) w2c[d] = w2[d * COUT + c];

    const int rowbase = (blockIdx.x * 4 + wv) * 8;

    for (int pair = 0; pair < 4; ++pair) {
        const int ra = rowbase + pair * 2;
#pragma unroll
        for (int rr = 0; rr < 2; ++rr) {
            const int row = ra + rr;
            const int b   = row >> 12;
            const float xi0 = x[row * 3 + 0];
            const float xi1 = x[row * 3 + 1];
            const float xi2 = x[row * 3 + 2];
#pragma unroll
            for (int k = 0; k < KNN; ++k) {
                int j = idx[row * KNN + k];               // wave-uniform
                const float* pj = x + ((size_t)b * N_ + j) * 3;
                float e3 = pj[0] - xi0, e4 = pj[1] - xi1, e5 = pj[2] - xi2;
                float h = b1c;
                h = fmaf(xi0, w1c[0], h); h = fmaf(xi1, w1c[1], h);
                h = fmaf(xi2, w1c[2], h); h = fmaf(e3,  w1c[3], h);
                h = fmaf(e4,  w1c[4], h); h = fmaf(e5,  w1c[5], h);
                h = fmaf(h, sc, sh);
                h2[wv][k][c][rr] = fmaxf(h, 0.0f);        // 2-way bank alias: free
            }
        }
        __syncthreads();   // uniform across the block's 4 waves

        float mxa = -INFINITY, mxb = -INFINITY;
        for (int k = 0; k < KNN; ++k) {
            float aa = b2c, ab = b2c;
#pragma unroll
            for (int d2 = 0; d2 < COUT / 2; ++d2) {
                float4 hv = *(const float4*)&h2[wv][k][d2 * 2][0]; // broadcast
                aa = fmaf(hv.x, w2c[d2 * 2 + 0], aa);
                ab = fmaf(hv.y, w2c[d2 * 2 + 0], ab);
                aa = fmaf(hv.z, w2c[d2 * 2 + 1], aa);
                ab = fmaf(hv.w, w2c[d2 * 2 + 1], ab);
            }
            mxa = fmaxf(mxa, aa); mxb = fmaxf(mxb, ab);
        }
        out[(size_t)ra * COUT + c]       = mxa;
        out[(size_t)(ra + 1) * COUT + c] = mxb;
        __syncthreads();   // protect h2 reuse next pair
    }
}

// ===========================================================================
extern "C" void kernel_launch(void* const* d_in, const int* in_sizes, int n_in,
                              void* d_out, int out_size, void* d_ws, size_t ws_size,
                              hipStream_t stream)
{
    const float* x     = (const float*)d_in[0];
    const float* w1    = (const float*)d_in[2];
    const float* b1    = (const float*)d_in[3];
    const float* gamma = (const float*)d_in[4];
    const float* beta  = (const float*)d_in[5];
    const float* w2    = (const float*)d_in[6];
    const float* b2    = (const float*)d_in[7];
    float* out = (float*)d_out;

    char*   ws          = (char*)d_ws;
    double* stats       = (double*)ws;
    float*  scale_shift = (float*)(ws + 256);
    int*    idx         = (int*)(ws + 1024);
    int*    perm        = (int*)(ws + 1024 + (size_t)B_ * N_ * KNN * 4);

    hipMemsetAsync(stats, 0, 27 * sizeof(double), stream);
    morton_bucket_kernel<<<B_, 1024, 0, stream>>>(x, perm);
    knn_inter_kernel<<<dim3(32, 16), 512, 0, stream>>>(x, perm, idx, stats);
    bn_prep_kernel<<<1, COUT, 0, stream>>>(stats, w1, b1, gamma, beta, scale_shift);
    mlp_max_kernel<<<(B_ * N_) / 32, 256, 0, stream>>>(x, idx, w1, b1, scale_shift,
                                                       w2, b2, out);
}